// Round 2
// baseline (667.097 us; speedup 1.0000x reference)
//
#include <hip/hip_runtime.h>

typedef unsigned short u16;
typedef unsigned int   u32;
typedef __attribute__((ext_vector_type(4))) float f32x4;
typedef __attribute__((ext_vector_type(8))) short short8;

#define DEV __device__ __forceinline__
#define AS1 __attribute__((address_space(1)))
#define AS3 __attribute__((address_space(3)))

DEV float bf2f(u16 u){ return __uint_as_float(((u32)u)<<16); }
DEV u16 f2bf(float f){ u32 u=__float_as_uint(f); return (u16)((u + 0x7fffu + ((u>>16)&1u))>>16); }
DEV void g2lds16(const void* g, void* l){
  __builtin_amdgcn_global_load_lds((const AS1 void*)g, (AS3 void*)l, 16, 0, 0);
}

// ---------------- f32 [K][N] -> bf16 [N][K] transpose ----------------
__global__ __launch_bounds__(256) void wt_kernel(const float* __restrict__ W,
                                                 u16* __restrict__ WT, int K, int N){
  __shared__ u16 tile[32][33];
  int n0 = blockIdx.x*32, k0 = blockIdx.y*32;
  int tx = threadIdx.x, ty = threadIdx.y;            // (32,8)
  #pragma unroll
  for (int i=0;i<4;++i){
    int k = ty + i*8;
    tile[k][tx] = f2bf(W[(size_t)(k0+k)*N + n0 + tx]);
  }
  __syncthreads();
  #pragma unroll
  for (int i=0;i<4;++i){
    int n = ty + i*8;
    WT[(size_t)(n0+n)*K + k0 + tx] = tile[tx][n];
  }
}

// ---------------- f32 -> bf16 elementwise ----------------
__global__ __launch_bounds__(256) void cvt_kernel(const float* __restrict__ in,
                                                  u16* __restrict__ out, long n){
  long i = (long)blockIdx.x*256 + threadIdx.x;
  if (i < n) out[i] = f2bf(in[i]);
}

// ---------------- sentinel fill (ws too small diagnostic) ----------------
__global__ __launch_bounds__(256) void fill_kernel(float* p, float v, long n){
  long i = (long)blockIdx.x*256 + threadIdx.x;
  if (i < n) p[i] = v;
}

// ---------------- KNN: per batch 40x40 dists, pick 8 smallest ----------------
__global__ __launch_bounds__(64) void knn_kernel(const float* __restrict__ verts,
                                                 unsigned char* __restrict__ nbr1,
                                                 unsigned char* __restrict__ nbr2){
  __shared__ float P[40][3];
  __shared__ float SQ[40];
  int b = blockIdx.x, t = threadIdx.x;
  if (t < 40){
    float x = verts[((size_t)b*40+t)*3+0];
    float y = verts[((size_t)b*40+t)*3+1];
    float z = verts[((size_t)b*40+t)*3+2];
    P[t][0]=x; P[t][1]=y; P[t][2]=z;
    SQ[t] = __fadd_rn(__fadd_rn(__fmul_rn(x,x),__fmul_rn(y,y)),__fmul_rn(z,z));
  }
  __syncthreads();
  if (t < 40){
    float x=P[t][0], y=P[t][1], z=P[t][2];
    float d[40];
    #pragma unroll 1
    for (int j=0;j<40;++j){
      // match reference rounding: ((-2*dot) + sq_varying) + sq_fixed
      float dot = __fadd_rn(__fadd_rn(__fmul_rn(x,P[j][0]),__fmul_rn(y,P[j][1])),
                            __fmul_rn(z,P[j][2]));
      d[j] = __fadd_rn(__fadd_rn(__fmul_rn(-2.f,dot), SQ[j]), SQ[t]);
    }
    unsigned long long chosen = 0ull;
    #pragma unroll 1
    for (int s=0;s<8;++s){
      float bd = 3.4e38f; int bj = 0;
      #pragma unroll 1
      for (int j=0;j<40;++j){
        if (!((chosen>>j)&1ull) && d[j] < bd){ bd = d[j]; bj = j; }
      }
      chosen |= (1ull<<bj);
      if (s < 4) nbr1[((size_t)b*40+t)*4+s] = (unsigned char)bj;
      nbr2[((size_t)b*40+t)*8+s] = (unsigned char)bj;
    }
  }
}

// ---------------- bf16 MFMA GEMM: C[M,N] = A[M,K] @ BT[N,K]^T + bias ----------------
// 128x128 tile, BK=32, 4 waves (2x2), 4x4 16x16x32 fragments per wave (m97 structure)
template<int RELU, int OUTBF>
__global__ __launch_bounds__(256, 2) void gemm_bt(const u16* __restrict__ A,
                                                  const u16* __restrict__ BT,
                                                  const float* __restrict__ bias,
                                                  void* __restrict__ Cout,
                                                  int M, int N, int K){
  __shared__ u16 As[128*32];
  __shared__ u16 Bs[128*32];
  const int tid  = threadIdx.x;
  const int wave = tid>>6, lane = tid&63;
  const int wr = (wave>>1)<<6, wc = (wave&1)<<6;
  const int row0 = blockIdx.x<<7, col0 = blockIdx.y<<7;
  f32x4 acc[4][4];
  #pragma unroll
  for (int i=0;i<4;++i)
    #pragma unroll
    for (int j=0;j<4;++j) acc[i][j] = (f32x4){0.f,0.f,0.f,0.f};

  const int rA = lane>>2;             // + c*64 + wave*16
  const int kk = (lane&3)<<3;
  const int fr = lane&15, fc = lane>>4;
  const short8* Asv = (const short8*)As;
  const short8* Bsv = (const short8*)Bs;

  for (int kt=0; kt<K; kt+=32){
    #pragma unroll
    for (int c=0;c<2;++c){
      int lo = c*4096 + wave*1024;             // wave-uniform LDS byte base
      int r  = c*64 + wave*16 + rA;
      g2lds16(A  + (size_t)(row0+r)*K + kt + kk, (char*)As + lo);
      g2lds16(BT + (size_t)(col0+r)*K + kt + kk, (char*)Bs + lo);
    }
    __syncthreads();                            // drains vmcnt(0) + barrier
    short8 a[4], b[4];
    #pragma unroll
    for (int i=0;i<4;++i){
      a[i] = Asv[(wr + i*16 + fr)*4 + fc];
      b[i] = Bsv[(wc + i*16 + fr)*4 + fc];
    }
    #pragma unroll
    for (int i=0;i<4;++i)
      #pragma unroll
      for (int j=0;j<4;++j)
        acc[i][j] = __builtin_amdgcn_mfma_f32_16x16x32_bf16(a[i], b[j], acc[i][j], 0,0,0);
    __syncthreads();
  }
  #pragma unroll
  for (int i=0;i<4;++i){
    int mrow = row0 + wr + i*16 + fc*4;
    #pragma unroll
    for (int j=0;j<4;++j){
      int ncol = col0 + wc + j*16 + fr;
      float bv = bias[ncol];
      #pragma unroll
      for (int r=0;r<4;++r){
        float v = acc[i][j][r] + bv;
        if (RELU) v = v > 0.f ? v : 0.f;
        if (OUTBF) ((u16*)Cout)[(size_t)(mrow+r)*N + ncol] = f2bf(v);
        else       ((float*)Cout)[(size_t)(mrow+r)*N + ncol] = v;
      }
    }
  }
}

// ---------------- sparse masked attention: one block per (b,h) ----------------
template<int KNB>
__global__ __launch_bounds__(256) void attn_kernel(const float* __restrict__ Q,
                                                   const float* __restrict__ Km,
                                                   const u16* __restrict__ V,
                                                   const unsigned char* __restrict__ nbr,
                                                   u16* __restrict__ O){
  __shared__ float att[40][8];
  __shared__ unsigned char nb[40][8];
  int b = blockIdx.x>>2, h = blockIdx.x&3;
  int tid = threadIdx.x, wave = tid>>6, lane = tid&63;
  // FIX (round 1 bug): 40*KNB can exceed blockDim (320 > 256 for KNB=8) -> grid-stride
  for (int t = tid; t < 40*KNB; t += 256)
    nb[t/KNB][t%KNB] = nbr[(size_t)b*40*KNB + t];
  __syncthreads();
  size_t base = ((size_t)b*40)*1024 + (size_t)h*256;
  // phase 1: 40*KNB logits, one wave per pair
  for (int p = wave; p < 40*KNB; p += 4){
    int i = p/KNB, jj = p - i*KNB;
    int j = nb[i][jj];
    const float* qr = Q  + base + (size_t)i*1024;
    const float* kr = Km + base + (size_t)j*1024;
    float s = 0.f;
    #pragma unroll
    for (int c=0;c<4;++c) s += qr[lane + c*64]*kr[lane + c*64];
    #pragma unroll
    for (int o=32;o;o>>=1) s += __shfl_xor(s, o);
    if (lane==0) att[i][jj] = s * 0.0625f;     // 1/sqrt(256)
  }
  __syncthreads();
  // phase 2: per-row softmax over the KNB unmasked entries
  if (tid < 40){
    float m = -1e30f;
    #pragma unroll
    for (int jj=0;jj<KNB;++jj) m = fmaxf(m, att[tid][jj]);
    float ee[KNB]; float sum = 0.f;
    #pragma unroll
    for (int jj=0;jj<KNB;++jj){ ee[jj] = expf(att[tid][jj]-m); sum += ee[jj]; }
    float inv = 1.f/sum;
    #pragma unroll
    for (int jj=0;jj<KNB;++jj) att[tid][jj] = ee[jj]*inv;
  }
  __syncthreads();
  // phase 3: O[i][d] = sum_j w_ij * V[j][d], d = tid (coalesced)
  int d = tid;
  #pragma unroll 1
  for (int i=0;i<40;++i){
    float o = 0.f;
    #pragma unroll
    for (int jj=0;jj<KNB;++jj){
      int j = nb[i][jj];
      o += att[i][jj] * bf2f(V[base + (size_t)j*1024 + d]);
    }
    O[base + (size_t)i*1024 + d] = f2bf(o);
  }
}

// ---------------- residual + LayerNorm (row = 512) ----------------
DEV float blockReduce(float v, float* red){
  #pragma unroll
  for (int o=32;o;o>>=1) v += __shfl_xor(v, o);
  int lane = threadIdx.x&63, w = threadIdx.x>>6;
  if (lane==0) red[w] = v;
  __syncthreads();
  float t = red[0]+red[1]+red[2]+red[3];
  __syncthreads();
  return t;
}

__global__ __launch_bounds__(256) void ln_kernel(const float* __restrict__ resf,
                                                 const float* __restrict__ delta,
                                                 const float* __restrict__ g,
                                                 const float* __restrict__ be,
                                                 u16* __restrict__ outb, int ostride, int ocol,
                                                 float* __restrict__ outf){
  __shared__ float red[4];
  int row = blockIdx.x, tid = threadIdx.x;
  size_t ib = (size_t)row*512;
  float x0 = resf[ib+tid]     + delta[ib+tid];
  float x1 = resf[ib+tid+256] + delta[ib+tid+256];
  float s = blockReduce(x0+x1, red);
  float mean = s*(1.f/512.f);
  float d0 = x0-mean, d1 = x1-mean;
  float q = blockReduce(d0*d0+d1*d1, red);
  float inv = 1.f/sqrtf(q*(1.f/512.f)+1e-5f);
  float r0 = d0*inv*g[tid]     + be[tid];
  float r1 = d1*inv*g[tid+256] + be[tid+256];
  size_t ob = (size_t)row*ostride + ocol;
  outb[ob+tid]     = f2bf(r0);
  outb[ob+tid+256] = f2bf(r1);
  if (outf){ outf[ib+tid] = r0; outf[ib+tid+256] = r1; }
}

// ---------------- BatchNorm (training stats over 10240 rows) ----------------
__global__ __launch_bounds__(512) void bn_part(const float* __restrict__ y,
                                               float* __restrict__ psum, float* __restrict__ psq){
  int c = threadIdx.x, blk = blockIdx.x;   // 64 blocks x 512 threads
  float s = 0.f, q = 0.f;
  for (int r = blk; r < 10240; r += 64){
    float v = y[(size_t)r*512 + c];
    s += v; q += v*v;
  }
  psum[blk*512+c] = s; psq[blk*512+c] = q;
}

__global__ __launch_bounds__(512) void bn_fin(const float* __restrict__ psum,
                                              const float* __restrict__ psq,
                                              const float* __restrict__ g,
                                              const float* __restrict__ b,
                                              float* __restrict__ scale, float* __restrict__ shift){
  int c = threadIdx.x;
  float s = 0.f, q = 0.f;
  for (int k=0;k<64;++k){ s += psum[k*512+c]; q += psq[k*512+c]; }
  float m = s*(1.f/10240.f);
  float var = q*(1.f/10240.f) - m*m;
  float sc = g[c]/sqrtf(var + 1e-5f);
  scale[c] = sc; shift[c] = b[c] - m*sc;
}

__global__ __launch_bounds__(256) void bn_apply(const float* __restrict__ y,
                                                const float* __restrict__ scale,
                                                const float* __restrict__ shift,
                                                u16* __restrict__ out){
  long i = (long)blockIdx.x*256 + threadIdx.x;
  if (i < (long)10240*512){
    int c = (int)(i & 511);
    float v = y[i]*scale[c] + shift[c];
    v = v > 0.f ? v : 0.2f*v;                 // LeakyReLU(0.2)
    out[i] = f2bf(v);
  }
}

extern "C" void kernel_launch(void* const* d_in, const int* in_sizes, int n_in,
                              void* d_out, int out_size, void* d_ws, size_t ws_size,
                              hipStream_t stream){
  const float* verts = (const float*)d_in[0];
  const float* F     = (const float*)d_in[1];
  const float* ew[2][16];
  for (int e=0;e<2;++e) for (int i=0;i<16;++i) ew[e][i] = (const float*)d_in[2+e*16+i];
  const float* fus_w1  = (const float*)d_in[34];
  const float* fus_b1  = (const float*)d_in[35];
  const float* fus_bng = (const float*)d_in[36];
  const float* fus_bnb = (const float*)d_in[37];
  const float* fus_w2  = (const float*)d_in[38];
  const float* fus_b2  = (const float*)d_in[39];

  const int M = 10240;
  size_t off = 0;
  auto alloc = [&](size_t bytes)->void*{
    void* p = (char*)d_ws + off; off = (off + bytes + 255) & ~(size_t)255; return p;
  };
  u16 *wtq[2],*wtk[2],*wtv[2],*wto[2],*wtw1[2],*wtw2[2];
  for (int e=0;e<2;++e){
    wtq[e]  = (u16*)alloc((size_t)512*1024*2);
    wtk[e]  = (u16*)alloc((size_t)512*1024*2);
    wtv[e]  = (u16*)alloc((size_t)512*1024*2);
    wto[e]  = (u16*)alloc((size_t)512*1024*2);
    wtw1[e] = (u16*)alloc((size_t)512*2048*2);
    wtw2[e] = (u16*)alloc((size_t)512*2048*2);
  }
  u16*  wtf1 = (u16*)alloc((size_t)1024*512*2);   // [N=512][K=1024]
  u16*  wtf2 = (u16*)alloc((size_t)512*512*2);
  u16*  Fb   = (u16*)alloc((size_t)M*512*2);
  float* QB  = (float*)alloc((size_t)M*1024*4);
  float* KB  = (float*)alloc((size_t)M*1024*4);
  u16*  VB   = (u16*)alloc((size_t)M*1024*2);
  u16*  H1   = (u16*)alloc((size_t)M*2048*2);
  float* PF  = (float*)alloc((size_t)M*512*4);
  u16*  X1b  = (u16*)alloc((size_t)M*512*2);
  u16*  YC   = (u16*)alloc((size_t)M*1024*2);
  unsigned char* nbr1 = (unsigned char*)alloc(256*40*4);
  unsigned char* nbr2 = (unsigned char*)alloc(256*40*8);
  float* psum = (float*)alloc(64*512*4);
  float* psq  = (float*)alloc(64*512*4);
  float* bnsc = (float*)alloc(512*4);
  float* bnsh = (float*)alloc(512*4);
  // time-disjoint aliases
  u16*  OB  = H1;          // attention out, dead before FFN1 writes H1
  float* X1f = QB;         // LN1 f32 out, dead before next encoder's Q GEMM
  float* Y1  = QB;         // fusion GEMM f32 out (post-encoders)
  u16*  Y2  = (u16*)KB;    // BN+leaky bf16 out

  if (off > ws_size){      // ws too small: distinguishable sentinel
    long n = out_size;
    fill_kernel<<<(unsigned)((n+255)/256),256,0,stream>>>((float*)d_out, 12345.0f, n);
    return;
  }

  // ---- prep: weight transposes, F->bf16, KNN ----
  for (int e=0;e<2;++e){
    wt_kernel<<<dim3(32,16),dim3(32,8),0,stream>>>(ew[e][0],  wtq[e],  512, 1024);
    wt_kernel<<<dim3(32,16),dim3(32,8),0,stream>>>(ew[e][2],  wtk[e],  512, 1024);
    wt_kernel<<<dim3(32,16),dim3(32,8),0,stream>>>(ew[e][4],  wtv[e],  512, 1024);
    wt_kernel<<<dim3(16,32),dim3(32,8),0,stream>>>(ew[e][6],  wto[e],  1024, 512);
    wt_kernel<<<dim3(64,16),dim3(32,8),0,stream>>>(ew[e][10], wtw1[e], 512, 2048);
    wt_kernel<<<dim3(16,64),dim3(32,8),0,stream>>>(ew[e][12], wtw2[e], 2048, 512);
  }
  wt_kernel<<<dim3(16,32),dim3(32,8),0,stream>>>(fus_w1, wtf1, 1024, 512);
  wt_kernel<<<dim3(16,16),dim3(32,8),0,stream>>>(fus_w2, wtf2, 512, 512);
  cvt_kernel<<<20480,256,0,stream>>>(F, Fb, (long)M*512);
  knn_kernel<<<256,64,0,stream>>>(verts, nbr1, nbr2);

  // ---- encoders ----
  for (int e=0;e<2;++e){
    gemm_bt<0,0><<<dim3(80,8),256,0,stream>>>(Fb, wtq[e], ew[e][1], QB, M, 1024, 512);
    gemm_bt<0,0><<<dim3(80,8),256,0,stream>>>(Fb, wtk[e], ew[e][3], KB, M, 1024, 512);
    gemm_bt<0,1><<<dim3(80,8),256,0,stream>>>(Fb, wtv[e], ew[e][5], VB, M, 1024, 512);
    if (e == 0) attn_kernel<4><<<1024,256,0,stream>>>(QB, KB, VB, nbr1, OB);
    else        attn_kernel<8><<<1024,256,0,stream>>>(QB, KB, VB, nbr2, OB);
    gemm_bt<0,0><<<dim3(80,4),256,0,stream>>>(OB, wto[e], ew[e][7], PF, M, 512, 1024);
    ln_kernel<<<M,256,0,stream>>>(F, PF, ew[e][8], ew[e][9], X1b, 512, 0, X1f);
    gemm_bt<1,1><<<dim3(80,16),256,0,stream>>>(X1b, wtw1[e], ew[e][11], H1, M, 2048, 512);
    gemm_bt<0,0><<<dim3(80,4),256,0,stream>>>(H1, wtw2[e], ew[e][13], PF, M, 512, 2048);
    ln_kernel<<<M,256,0,stream>>>(X1f, PF, ew[e][14], ew[e][15], YC, 1024, e*512, nullptr);
  }

  // ---- fusion ----
  gemm_bt<0,0><<<dim3(80,4),256,0,stream>>>(YC, wtf1, fus_b1, Y1, M, 512, 1024);
  bn_part<<<64,512,0,stream>>>(Y1, psum, psq);
  bn_fin<<<1,512,0,stream>>>(psum, psq, fus_bng, fus_bnb, bnsc, bnsh);
  bn_apply<<<20480,256,0,stream>>>(Y1, bnsc, bnsh, Y2);
  gemm_bt<0,0><<<dim3(80,4),256,0,stream>>>(Y2, wtf2, fus_b2, d_out, M, 512, 512);
}

// Round 3
// 630.640 us; speedup vs baseline: 1.0578x; 1.0578x over previous
//
#include <hip/hip_runtime.h>

typedef unsigned short u16;
typedef unsigned int   u32;
typedef __attribute__((ext_vector_type(4))) float f32x4;
typedef __attribute__((ext_vector_type(8))) short short8;
typedef __attribute__((ext_vector_type(4))) unsigned short u16x4;

#define DEV __device__ __forceinline__
#define AS1 __attribute__((address_space(1)))
#define AS3 __attribute__((address_space(3)))

DEV float bf2f(u16 u){ return __uint_as_float(((u32)u)<<16); }
DEV u16 f2bf(float f){ u32 u=__float_as_uint(f); return (u16)((u + 0x7fffu + ((u>>16)&1u))>>16); }
DEV void g2lds16(const void* g, void* l){
  __builtin_amdgcn_global_load_lds((const AS1 void*)g, (AS3 void*)l, 16, 0, 0);
}

// ---------------- f32 [K][N] -> bf16 [N][K] transpose ----------------
__global__ __launch_bounds__(256) void wt_kernel(const float* __restrict__ W,
                                                 u16* __restrict__ WT, int K, int N){
  __shared__ u16 tile[32][33];
  int n0 = blockIdx.x*32, k0 = blockIdx.y*32;
  int tx = threadIdx.x, ty = threadIdx.y;            // (32,8)
  #pragma unroll
  for (int i=0;i<4;++i){
    int k = ty + i*8;
    tile[k][tx] = f2bf(W[(size_t)(k0+k)*N + n0 + tx]);
  }
  __syncthreads();
  #pragma unroll
  for (int i=0;i<4;++i){
    int n = ty + i*8;
    WT[(size_t)(n0+n)*K + k0 + tx] = tile[tx][n];
  }
}

// ---------------- f32 -> bf16 elementwise ----------------
__global__ __launch_bounds__(256) void cvt_kernel(const float* __restrict__ in,
                                                  u16* __restrict__ out, long n){
  long i = (long)blockIdx.x*256 + threadIdx.x;
  if (i < n) out[i] = f2bf(in[i]);
}

// ---------------- sentinel fill (ws too small diagnostic) ----------------
__global__ __launch_bounds__(256) void fill_kernel(float* p, float v, long n){
  long i = (long)blockIdx.x*256 + threadIdx.x;
  if (i < n) p[i] = v;
}

// ---------------- KNN: one wave per (batch,row), d per-lane in registers ----------------
__global__ __launch_bounds__(256) void knn_kernel(const float* __restrict__ verts,
                                                  unsigned char* __restrict__ nbr1,
                                                  unsigned char* __restrict__ nbr2){
  __shared__ float P[40][3];
  __shared__ float SQ[40];
  int b = blockIdx.x, tid = threadIdx.x, wave = tid>>6, lane = tid&63;
  if (tid < 40){
    float x = verts[((size_t)b*40+tid)*3+0];
    float y = verts[((size_t)b*40+tid)*3+1];
    float z = verts[((size_t)b*40+tid)*3+2];
    P[tid][0]=x; P[tid][1]=y; P[tid][2]=z;
    SQ[tid] = __fadd_rn(__fadd_rn(__fmul_rn(x,x),__fmul_rn(y,y)),__fmul_rn(z,z));
  }
  __syncthreads();
  // wave handles rows i = wave, wave+4, ... ; lane j owns d[i][j]
  for (int i = wave; i < 40; i += 4){
    float d = 3.0e38f;
    if (lane < 40){
      int j = lane;
      // reference rounding: ((-2*dot) + sq[j]) + sq[i], dot = (x*x'+y*y')+z*z'
      float dot = __fadd_rn(__fadd_rn(__fmul_rn(P[i][0],P[j][0]),
                                      __fmul_rn(P[i][1],P[j][1])),
                            __fmul_rn(P[i][2],P[j][2]));
      d = __fadd_rn(__fadd_rn(__fmul_rn(-2.f,dot), SQ[j]), SQ[i]);
    }
    bool taken = false;
    #pragma unroll
    for (int s=0;s<8;++s){
      float v = taken ? 3.0e38f : d;
      float m = v;
      #pragma unroll
      for (int o=32;o;o>>=1) m = fminf(m, __shfl_xor(m, o));
      unsigned long long mask = __ballot(v == m);
      int bj = __ffsll((unsigned long long)mask) - 1;   // lowest index among ties (stable, matches top_k)
      if (lane == bj) taken = true;
      if (lane == 0){
        if (s < 4) nbr1[((size_t)b*40+i)*4+s] = (unsigned char)bj;
        nbr2[((size_t)b*40+i)*8+s] = (unsigned char)bj;
      }
    }
  }
}

// ---------------- bf16 MFMA GEMM: C[M,N] = A[M,K] @ BT[N,K]^T + bias ----------------
// 128x128 tile, BK=32, 4 waves (2x2), 4x4 16x16x32 fragments per wave (m97 structure)
template<int RELU, int OUTBF>
__global__ __launch_bounds__(256, 2) void gemm_bt(const u16* __restrict__ A,
                                                  const u16* __restrict__ BT,
                                                  const float* __restrict__ bias,
                                                  void* __restrict__ Cout,
                                                  int M, int N, int K){
  __shared__ u16 As[128*32];
  __shared__ u16 Bs[128*32];
  const int tid  = threadIdx.x;
  const int wave = tid>>6, lane = tid&63;
  const int wr = (wave>>1)<<6, wc = (wave&1)<<6;
  const int row0 = blockIdx.x<<7, col0 = blockIdx.y<<7;
  f32x4 acc[4][4];
  #pragma unroll
  for (int i=0;i<4;++i)
    #pragma unroll
    for (int j=0;j<4;++j) acc[i][j] = (f32x4){0.f,0.f,0.f,0.f};

  const int rA = lane>>2;             // + c*64 + wave*16
  const int kk = (lane&3)<<3;
  const int fr = lane&15, fc = lane>>4;
  const short8* Asv = (const short8*)As;
  const short8* Bsv = (const short8*)Bs;

  for (int kt=0; kt<K; kt+=32){
    #pragma unroll
    for (int c=0;c<2;++c){
      int lo = c*4096 + wave*1024;             // wave-uniform LDS byte base
      int r  = c*64 + wave*16 + rA;
      g2lds16(A  + (size_t)(row0+r)*K + kt + kk, (char*)As + lo);
      g2lds16(BT + (size_t)(col0+r)*K + kt + kk, (char*)Bs + lo);
    }
    __syncthreads();                            // drains vmcnt(0) + barrier
    short8 a[4], b[4];
    #pragma unroll
    for (int i=0;i<4;++i){
      a[i] = Asv[(wr + i*16 + fr)*4 + fc];
      b[i] = Bsv[(wc + i*16 + fr)*4 + fc];
    }
    #pragma unroll
    for (int i=0;i<4;++i)
      #pragma unroll
      for (int j=0;j<4;++j)
        acc[i][j] = __builtin_amdgcn_mfma_f32_16x16x32_bf16(a[i], b[j], acc[i][j], 0,0,0);
    __syncthreads();
  }
  #pragma unroll
  for (int i=0;i<4;++i){
    int mrow = row0 + wr + i*16 + fc*4;
    #pragma unroll
    for (int j=0;j<4;++j){
      int ncol = col0 + wc + j*16 + fr;
      float bv = bias[ncol];
      #pragma unroll
      for (int r=0;r<4;++r){
        float v = acc[i][j][r] + bv;
        if (RELU) v = v > 0.f ? v : 0.f;
        if (OUTBF) ((u16*)Cout)[(size_t)(mrow+r)*N + ncol] = f2bf(v);
        else       ((float*)Cout)[(size_t)(mrow+r)*N + ncol] = v;
      }
    }
  }
}

// ---------------- sparse masked attention: wave-local, no LDS/barriers ----------------
// block = 4 waves per (b,h); wave owns whole rows: QK^T (f32) -> softmax -> PV, all in-wave
template<int KNB>
__global__ __launch_bounds__(256) void attn_kernel(const float* __restrict__ Q,
                                                   const float* __restrict__ Km,
                                                   const u16* __restrict__ V,
                                                   const unsigned char* __restrict__ nbr,
                                                   u16* __restrict__ O){
  int b = blockIdx.x>>2, h = blockIdx.x&3;
  int tid = threadIdx.x, wave = tid>>6, lane = tid&63;
  size_t base = ((size_t)b*40)*1024 + (size_t)h*256;
  for (int i = wave; i < 40; i += 4){
    int js[KNB];
    #pragma unroll
    for (int jj=0;jj<KNB;++jj) js[jj] = nbr[((size_t)b*40+i)*KNB + jj];
    const f32x4 q = *(const f32x4*)(Q + base + (size_t)i*1024 + lane*4);
    float s[KNB];
    #pragma unroll
    for (int jj=0;jj<KNB;++jj){
      const f32x4 k = *(const f32x4*)(Km + base + (size_t)js[jj]*1024 + lane*4);
      s[jj] = q.x*k.x + q.y*k.y + q.z*k.z + q.w*k.w;
    }
    #pragma unroll
    for (int jj=0;jj<KNB;++jj){
      #pragma unroll
      for (int o=32;o;o>>=1) s[jj] += __shfl_xor(s[jj], o);
      s[jj] *= 0.0625f;                       // 1/sqrt(256)
    }
    float m = s[0];
    #pragma unroll
    for (int jj=1;jj<KNB;++jj) m = fmaxf(m, s[jj]);
    float sum = 0.f;
    #pragma unroll
    for (int jj=0;jj<KNB;++jj){ s[jj] = expf(s[jj]-m); sum += s[jj]; }
    float inv = 1.f/sum;
    float o0=0.f,o1=0.f,o2=0.f,o3=0.f;
    #pragma unroll
    for (int jj=0;jj<KNB;++jj){
      float w = s[jj]*inv;
      u16x4 v = *(const u16x4*)(V + base + (size_t)js[jj]*1024 + lane*4);
      o0 += w*bf2f(v.x); o1 += w*bf2f(v.y); o2 += w*bf2f(v.z); o3 += w*bf2f(v.w);
    }
    u16x4 r; r.x=f2bf(o0); r.y=f2bf(o1); r.z=f2bf(o2); r.w=f2bf(o3);
    *(u16x4*)(O + base + (size_t)i*1024 + lane*4) = r;
  }
}

// ---------------- residual + LayerNorm (row = 512) ----------------
DEV float blockReduce(float v, float* red){
  #pragma unroll
  for (int o=32;o;o>>=1) v += __shfl_xor(v, o);
  int lane = threadIdx.x&63, w = threadIdx.x>>6;
  if (lane==0) red[w] = v;
  __syncthreads();
  float t = red[0]+red[1]+red[2]+red[3];
  __syncthreads();
  return t;
}

__global__ __launch_bounds__(256) void ln_kernel(const float* __restrict__ resf,
                                                 const float* __restrict__ delta,
                                                 const float* __restrict__ g,
                                                 const float* __restrict__ be,
                                                 u16* __restrict__ outb, int ostride, int ocol,
                                                 float* __restrict__ outf){
  __shared__ float red[4];
  int row = blockIdx.x, tid = threadIdx.x;
  size_t ib = (size_t)row*512;
  float x0 = resf[ib+tid]     + delta[ib+tid];
  float x1 = resf[ib+tid+256] + delta[ib+tid+256];
  float s = blockReduce(x0+x1, red);
  float mean = s*(1.f/512.f);
  float d0 = x0-mean, d1 = x1-mean;
  float q = blockReduce(d0*d0+d1*d1, red);
  float inv = 1.f/sqrtf(q*(1.f/512.f)+1e-5f);
  float r0 = d0*inv*g[tid]     + be[tid];
  float r1 = d1*inv*g[tid+256] + be[tid+256];
  size_t ob = (size_t)row*ostride + ocol;
  outb[ob+tid]     = f2bf(r0);
  outb[ob+tid+256] = f2bf(r1);
  if (outf){ outf[ib+tid] = r0; outf[ib+tid+256] = r1; }
}

// ---------------- BatchNorm (training stats over 10240 rows) ----------------
__global__ __launch_bounds__(512) void bn_part(const float* __restrict__ y,
                                               float* __restrict__ psum, float* __restrict__ psq){
  int c = threadIdx.x, blk = blockIdx.x;   // 64 blocks x 512 threads
  float s = 0.f, q = 0.f;
  for (int r = blk; r < 10240; r += 64){
    float v = y[(size_t)r*512 + c];
    s += v; q += v*v;
  }
  psum[blk*512+c] = s; psq[blk*512+c] = q;
}

__global__ __launch_bounds__(512) void bn_fin(const float* __restrict__ psum,
                                              const float* __restrict__ psq,
                                              const float* __restrict__ g,
                                              const float* __restrict__ b,
                                              float* __restrict__ scale, float* __restrict__ shift){
  int c = threadIdx.x;
  float s = 0.f, q = 0.f;
  for (int k=0;k<64;++k){ s += psum[k*512+c]; q += psq[k*512+c]; }
  float m = s*(1.f/10240.f);
  float var = q*(1.f/10240.f) - m*m;
  float sc = g[c]/sqrtf(var + 1e-5f);
  scale[c] = sc; shift[c] = b[c] - m*sc;
}

__global__ __launch_bounds__(256) void bn_apply(const float* __restrict__ y,
                                                const float* __restrict__ scale,
                                                const float* __restrict__ shift,
                                                u16* __restrict__ out){
  long i = (long)blockIdx.x*256 + threadIdx.x;
  if (i < (long)10240*512){
    int c = (int)(i & 511);
    float v = y[i]*scale[c] + shift[c];
    v = v > 0.f ? v : 0.2f*v;                 // LeakyReLU(0.2)
    out[i] = f2bf(v);
  }
}

extern "C" void kernel_launch(void* const* d_in, const int* in_sizes, int n_in,
                              void* d_out, int out_size, void* d_ws, size_t ws_size,
                              hipStream_t stream){
  const float* verts = (const float*)d_in[0];
  const float* F     = (const float*)d_in[1];
  const float* ew[2][16];
  for (int e=0;e<2;++e) for (int i=0;i<16;++i) ew[e][i] = (const float*)d_in[2+e*16+i];
  const float* fus_w1  = (const float*)d_in[34];
  const float* fus_b1  = (const float*)d_in[35];
  const float* fus_bng = (const float*)d_in[36];
  const float* fus_bnb = (const float*)d_in[37];
  const float* fus_w2  = (const float*)d_in[38];
  const float* fus_b2  = (const float*)d_in[39];

  const int M = 10240;
  size_t off = 0;
  auto alloc = [&](size_t bytes)->void*{
    void* p = (char*)d_ws + off; off = (off + bytes + 255) & ~(size_t)255; return p;
  };
  u16 *wtq[2],*wtk[2],*wtv[2],*wto[2],*wtw1[2],*wtw2[2];
  for (int e=0;e<2;++e){
    wtq[e]  = (u16*)alloc((size_t)512*1024*2);
    wtk[e]  = (u16*)alloc((size_t)512*1024*2);
    wtv[e]  = (u16*)alloc((size_t)512*1024*2);
    wto[e]  = (u16*)alloc((size_t)512*1024*2);
    wtw1[e] = (u16*)alloc((size_t)512*2048*2);
    wtw2[e] = (u16*)alloc((size_t)512*2048*2);
  }
  u16*  wtf1 = (u16*)alloc((size_t)1024*512*2);   // [N=512][K=1024]
  u16*  wtf2 = (u16*)alloc((size_t)512*512*2);
  u16*  Fb   = (u16*)alloc((size_t)M*512*2);
  float* QB  = (float*)alloc((size_t)M*1024*4);
  float* KB  = (float*)alloc((size_t)M*1024*4);
  u16*  VB   = (u16*)alloc((size_t)M*1024*2);
  u16*  H1   = (u16*)alloc((size_t)M*2048*2);
  float* PF  = (float*)alloc((size_t)M*512*4);
  u16*  X1b  = (u16*)alloc((size_t)M*512*2);
  u16*  YC   = (u16*)alloc((size_t)M*1024*2);
  unsigned char* nbr1 = (unsigned char*)alloc(256*40*4);
  unsigned char* nbr2 = (unsigned char*)alloc(256*40*8);
  float* psum = (float*)alloc(64*512*4);
  float* psq  = (float*)alloc(64*512*4);
  float* bnsc = (float*)alloc(512*4);
  float* bnsh = (float*)alloc(512*4);
  // time-disjoint aliases
  u16*  OB  = H1;          // attention out, dead before FFN1 writes H1
  float* X1f = QB;         // LN1 f32 out, dead before next encoder's Q GEMM
  float* Y1  = QB;         // fusion GEMM f32 out (post-encoders)
  u16*  Y2  = (u16*)KB;    // BN+leaky bf16 out

  if (off > ws_size){      // ws too small: distinguishable sentinel
    long n = out_size;
    fill_kernel<<<(unsigned)((n+255)/256),256,0,stream>>>((float*)d_out, 12345.0f, n);
    return;
  }

  // ---- prep: weight transposes, F->bf16, KNN ----
  for (int e=0;e<2;++e){
    wt_kernel<<<dim3(32,16),dim3(32,8),0,stream>>>(ew[e][0],  wtq[e],  512, 1024);
    wt_kernel<<<dim3(32,16),dim3(32,8),0,stream>>>(ew[e][2],  wtk[e],  512, 1024);
    wt_kernel<<<dim3(32,16),dim3(32,8),0,stream>>>(ew[e][4],  wtv[e],  512, 1024);
    wt_kernel<<<dim3(16,32),dim3(32,8),0,stream>>>(ew[e][6],  wto[e],  1024, 512);
    wt_kernel<<<dim3(64,16),dim3(32,8),0,stream>>>(ew[e][10], wtw1[e], 512, 2048);
    wt_kernel<<<dim3(16,64),dim3(32,8),0,stream>>>(ew[e][12], wtw2[e], 2048, 512);
  }
  wt_kernel<<<dim3(16,32),dim3(32,8),0,stream>>>(fus_w1, wtf1, 1024, 512);
  wt_kernel<<<dim3(16,16),dim3(32,8),0,stream>>>(fus_w2, wtf2, 512, 512);
  cvt_kernel<<<20480,256,0,stream>>>(F, Fb, (long)M*512);
  knn_kernel<<<256,256,0,stream>>>(verts, nbr1, nbr2);

  // ---- encoders ----
  for (int e=0;e<2;++e){
    gemm_bt<0,0><<<dim3(80,8),256,0,stream>>>(Fb, wtq[e], ew[e][1], QB, M, 1024, 512);
    gemm_bt<0,0><<<dim3(80,8),256,0,stream>>>(Fb, wtk[e], ew[e][3], KB, M, 1024, 512);
    gemm_bt<0,1><<<dim3(80,8),256,0,stream>>>(Fb, wtv[e], ew[e][5], VB, M, 1024, 512);
    if (e == 0) attn_kernel<4><<<1024,256,0,stream>>>(QB, KB, VB, nbr1, OB);
    else        attn_kernel<8><<<1024,256,0,stream>>>(QB, KB, VB, nbr2, OB);
    gemm_bt<0,0><<<dim3(80,4),256,0,stream>>>(OB, wto[e], ew[e][7], PF, M, 512, 1024);
    ln_kernel<<<M,256,0,stream>>>(F, PF, ew[e][8], ew[e][9], X1b, 512, 0, X1f);
    gemm_bt<1,1><<<dim3(80,16),256,0,stream>>>(X1b, wtw1[e], ew[e][11], H1, M, 2048, 512);
    gemm_bt<0,0><<<dim3(80,4),256,0,stream>>>(H1, wtw2[e], ew[e][13], PF, M, 512, 2048);
    ln_kernel<<<M,256,0,stream>>>(X1f, PF, ew[e][14], ew[e][15], YC, 1024, e*512, nullptr);
  }

  // ---- fusion ----
  gemm_bt<0,0><<<dim3(80,4),256,0,stream>>>(YC, wtf1, fus_b1, Y1, M, 512, 1024);
  bn_part<<<64,512,0,stream>>>(Y1, psum, psq);
  bn_fin<<<1,512,0,stream>>>(psum, psq, fus_bng, fus_bnb, bnsc, bnsh);
  bn_apply<<<20480,256,0,stream>>>(Y1, bnsc, bnsh, Y2);
  gemm_bt<0,0><<<dim3(80,4),256,0,stream>>>(Y2, wtf2, fus_b2, d_out, M, 512, 512);
}

// Round 4
// 566.044 us; speedup vs baseline: 1.1785x; 1.1141x over previous
//
#include <hip/hip_runtime.h>

typedef unsigned short u16;
typedef unsigned int   u32;
typedef __attribute__((ext_vector_type(4))) float f32x4;
typedef __attribute__((ext_vector_type(8))) short short8;
typedef __attribute__((ext_vector_type(4))) unsigned short u16x4;

#define DEV __device__ __forceinline__
#define AS1 __attribute__((address_space(1)))
#define AS3 __attribute__((address_space(3)))

DEV float bf2f(u16 u){ return __uint_as_float(((u32)u)<<16); }
DEV u16 f2bf(float f){ u32 u=__float_as_uint(f); return (u16)((u + 0x7fffu + ((u>>16)&1u))>>16); }
DEV void g2lds16(const void* g, void* l){
  __builtin_amdgcn_global_load_lds((const AS1 void*)g, (AS3 void*)l, 16, 0, 0);
}

// ---------------- f32 [K][N] -> bf16 [N][K] transpose ----------------
__global__ __launch_bounds__(256) void wt_kernel(const float* __restrict__ W,
                                                 u16* __restrict__ WT, int K, int N){
  __shared__ u16 tile[32][33];
  int n0 = blockIdx.x*32, k0 = blockIdx.y*32;
  int tx = threadIdx.x, ty = threadIdx.y;            // (32,8)
  #pragma unroll
  for (int i=0;i<4;++i){
    int k = ty + i*8;
    tile[k][tx] = f2bf(W[(size_t)(k0+k)*N + n0 + tx]);
  }
  __syncthreads();
  #pragma unroll
  for (int i=0;i<4;++i){
    int n = ty + i*8;
    WT[(size_t)(n0+n)*K + k0 + tx] = tile[tx][n];
  }
}

// ---------------- f32 -> bf16 elementwise (x4 vectorized) ----------------
__global__ __launch_bounds__(256) void cvt_kernel(const float* __restrict__ in,
                                                  u16* __restrict__ out, long n4){
  long i = ((long)blockIdx.x*256 + threadIdx.x);
  if (i < n4){
    f32x4 v = *(const f32x4*)(in + i*4);
    u16x4 r; r.x=f2bf(v.x); r.y=f2bf(v.y); r.z=f2bf(v.z); r.w=f2bf(v.w);
    *(u16x4*)(out + i*4) = r;
  }
}

// ---------------- concat 3 bias vectors [1024] -> [3072] ----------------
__global__ __launch_bounds__(256) void catb_kernel(const float* __restrict__ a,
                                                   const float* __restrict__ b,
                                                   const float* __restrict__ c,
                                                   float* __restrict__ dst){
  int i = blockIdx.x*256 + threadIdx.x;
  if (i < 1024) dst[i] = a[i];
  else if (i < 2048) dst[i] = b[i-1024];
  else if (i < 3072) dst[i] = c[i-2048];
}

// ---------------- sentinel fill (ws too small diagnostic) ----------------
__global__ __launch_bounds__(256) void fill_kernel(float* p, float v, long n){
  long i = (long)blockIdx.x*256 + threadIdx.x;
  if (i < n) p[i] = v;
}

// ---------------- KNN: one wave per (batch,row), d per-lane in registers ----------------
__global__ __launch_bounds__(256) void knn_kernel(const float* __restrict__ verts,
                                                  unsigned char* __restrict__ nbr1,
                                                  unsigned char* __restrict__ nbr2){
  __shared__ float P[40][3];
  __shared__ float SQ[40];
  int b = blockIdx.x, tid = threadIdx.x, wave = tid>>6, lane = tid&63;
  if (tid < 40){
    float x = verts[((size_t)b*40+tid)*3+0];
    float y = verts[((size_t)b*40+tid)*3+1];
    float z = verts[((size_t)b*40+tid)*3+2];
    P[tid][0]=x; P[tid][1]=y; P[tid][2]=z;
    SQ[tid] = __fadd_rn(__fadd_rn(__fmul_rn(x,x),__fmul_rn(y,y)),__fmul_rn(z,z));
  }
  __syncthreads();
  for (int i = wave; i < 40; i += 4){
    float d = 3.0e38f;
    if (lane < 40){
      int j = lane;
      float dot = __fadd_rn(__fadd_rn(__fmul_rn(P[i][0],P[j][0]),
                                      __fmul_rn(P[i][1],P[j][1])),
                            __fmul_rn(P[i][2],P[j][2]));
      d = __fadd_rn(__fadd_rn(__fmul_rn(-2.f,dot), SQ[j]), SQ[i]);
    }
    bool taken = false;
    #pragma unroll
    for (int s=0;s<8;++s){
      float v = taken ? 3.0e38f : d;
      float m = v;
      #pragma unroll
      for (int o=32;o;o>>=1) m = fminf(m, __shfl_xor(m, o));
      unsigned long long mask = __ballot(v == m);
      int bj = __ffsll((unsigned long long)mask) - 1;   // lowest index among ties (stable)
      if (lane == bj) taken = true;
      if (lane == 0){
        if (s < 4) nbr1[((size_t)b*40+i)*4+s] = (unsigned char)bj;
        nbr2[((size_t)b*40+i)*8+s] = (unsigned char)bj;
      }
    }
  }
}

// ---------------- bf16 MFMA GEMM: C[M,N] = A[M,K] @ BT[N,K]^T + bias ----------------
// 128x128 tile, BK=32, 4 waves (2x2), 4x4 16x16x32 fragments per wave (m97 structure)
template<int RELU, int OUTBF>
__global__ __launch_bounds__(256, 2) void gemm_bt(const u16* __restrict__ A,
                                                  const u16* __restrict__ BT,
                                                  const float* __restrict__ bias,
                                                  void* __restrict__ Cout,
                                                  int M, int N, int K){
  __shared__ u16 As[128*32];
  __shared__ u16 Bs[128*32];
  const int tid  = threadIdx.x;
  const int wave = tid>>6, lane = tid&63;
  const int wr = (wave>>1)<<6, wc = (wave&1)<<6;
  const int row0 = blockIdx.x<<7, col0 = blockIdx.y<<7;
  f32x4 acc[4][4];
  #pragma unroll
  for (int i=0;i<4;++i)
    #pragma unroll
    for (int j=0;j<4;++j) acc[i][j] = (f32x4){0.f,0.f,0.f,0.f};

  const int rA = lane>>2;             // + c*64 + wave*16
  const int kk = (lane&3)<<3;
  const int fr = lane&15, fc = lane>>4;
  const short8* Asv = (const short8*)As;
  const short8* Bsv = (const short8*)Bs;

  for (int kt=0; kt<K; kt+=32){
    #pragma unroll
    for (int c=0;c<2;++c){
      int lo = c*4096 + wave*1024;             // wave-uniform LDS byte base
      int r  = c*64 + wave*16 + rA;
      g2lds16(A  + (size_t)(row0+r)*K + kt + kk, (char*)As + lo);
      g2lds16(BT + (size_t)(col0+r)*K + kt + kk, (char*)Bs + lo);
    }
    __syncthreads();                            // drains vmcnt(0) + barrier
    short8 a[4], b[4];
    #pragma unroll
    for (int i=0;i<4;++i){
      a[i] = Asv[(wr + i*16 + fr)*4 + fc];
      b[i] = Bsv[(wc + i*16 + fr)*4 + fc];
    }
    #pragma unroll
    for (int i=0;i<4;++i)
      #pragma unroll
      for (int j=0;j<4;++j)
        acc[i][j] = __builtin_amdgcn_mfma_f32_16x16x32_bf16(a[i], b[j], acc[i][j], 0,0,0);
    __syncthreads();
  }
  #pragma unroll
  for (int i=0;i<4;++i){
    int mrow = row0 + wr + i*16 + fc*4;
    #pragma unroll
    for (int j=0;j<4;++j){
      int ncol = col0 + wc + j*16 + fr;
      float bv = bias[ncol];
      #pragma unroll
      for (int r=0;r<4;++r){
        float v = acc[i][j][r] + bv;
        if (RELU) v = v > 0.f ? v : 0.f;
        if (OUTBF) ((u16*)Cout)[(size_t)(mrow+r)*N + ncol] = f2bf(v);
        else       ((float*)Cout)[(size_t)(mrow+r)*N + ncol] = v;
      }
    }
  }
}

// ---------------- sparse masked attention: K/V staged in LDS, all-bf16 inputs ----------------
// block per (b,h), 4 waves; QKV combined [M][3072]: Q at h*256, K at 1024+h*256, V at 2048+h*256
template<int KNB>
__global__ __launch_bounds__(256) void attn_kernel(const u16* __restrict__ QKV,
                                                   const unsigned char* __restrict__ nbr,
                                                   u16* __restrict__ O){
  __shared__ u16 KV[2][40*256];    // [0]=K rows, [1]=V rows (bf16)
  int b = blockIdx.x>>2, h = blockIdx.x&3;
  int tid = threadIdx.x, wave = tid>>6, lane = tid&63;
  const size_t rowb = (size_t)b*40;
  for (int c = tid; c < 1280; c += 256){          // 40 rows x 32 chunks of 16B
    int row = c >> 5, col = (c & 31) << 3;
    size_t src = (rowb+row)*3072 + h*256 + col;
    *(short8*)&KV[0][row*256+col] = *(const short8*)(QKV + src + 1024);
    *(short8*)&KV[1][row*256+col] = *(const short8*)(QKV + src + 2048);
  }
  __syncthreads();
  for (int i = wave; i < 40; i += 4){
    int js[KNB];
    if (KNB == 4){
      u32 p = *(const u32*)(nbr + (rowb+i)*4);
      js[0]=p&255; js[1]=(p>>8)&255; js[2]=(p>>16)&255; js[3]=(p>>24)&255;
    } else {
      u32 p0 = *(const u32*)(nbr + (rowb+i)*8);
      u32 p1 = *(const u32*)(nbr + (rowb+i)*8 + 4);
      js[0]=p0&255; js[1]=(p0>>8)&255; js[2]=(p0>>16)&255; js[3]=(p0>>24)&255;
      js[4]=p1&255; js[5]=(p1>>8)&255; js[6]=(p1>>16)&255; js[7]=(p1>>24)&255;
    }
    u16x4 qv = *(const u16x4*)(QKV + (rowb+i)*3072 + h*256 + lane*4);
    float q0=bf2f(qv.x), q1=bf2f(qv.y), q2=bf2f(qv.z), q3=bf2f(qv.w);
    float s[KNB];
    #pragma unroll
    for (int jj=0;jj<KNB;++jj){
      u16x4 kv = *(const u16x4*)&KV[0][js[jj]*256 + lane*4];
      s[jj] = q0*bf2f(kv.x) + q1*bf2f(kv.y) + q2*bf2f(kv.z) + q3*bf2f(kv.w);
    }
    #pragma unroll
    for (int jj=0;jj<KNB;++jj){
      #pragma unroll
      for (int o=32;o;o>>=1) s[jj] += __shfl_xor(s[jj], o);
      s[jj] *= 0.0625f;                       // 1/sqrt(256)
    }
    float m = s[0];
    #pragma unroll
    for (int jj=1;jj<KNB;++jj) m = fmaxf(m, s[jj]);
    float sum = 0.f;
    #pragma unroll
    for (int jj=0;jj<KNB;++jj){ s[jj] = expf(s[jj]-m); sum += s[jj]; }
    float inv = 1.f/sum;
    float o0=0.f,o1=0.f,o2=0.f,o3=0.f;
    #pragma unroll
    for (int jj=0;jj<KNB;++jj){
      float w = s[jj]*inv;
      u16x4 vv = *(const u16x4*)&KV[1][js[jj]*256 + lane*4];
      o0 += w*bf2f(vv.x); o1 += w*bf2f(vv.y); o2 += w*bf2f(vv.z); o3 += w*bf2f(vv.w);
    }
    u16x4 r; r.x=f2bf(o0); r.y=f2bf(o1); r.z=f2bf(o2); r.w=f2bf(o3);
    *(u16x4*)(O + (rowb+i)*1024 + h*256 + lane*4) = r;
  }
}

// ---------------- residual + LayerNorm (row = 512), float2-vectorized ----------------
DEV float blockReduce(float v, float* red){
  #pragma unroll
  for (int o=32;o;o>>=1) v += __shfl_xor(v, o);
  int lane = threadIdx.x&63, w = threadIdx.x>>6;
  if (lane==0) red[w] = v;
  __syncthreads();
  float t = red[0]+red[1]+red[2]+red[3];
  __syncthreads();
  return t;
}

__global__ __launch_bounds__(256) void ln_kernel(const float* __restrict__ resf,
                                                 const float* __restrict__ delta,
                                                 const float* __restrict__ g,
                                                 const float* __restrict__ be,
                                                 u16* __restrict__ outb, int ostride, int ocol,
                                                 float* __restrict__ outf){
  __shared__ float red[4];
  int row = blockIdx.x, tid = threadIdx.x;
  size_t ib = (size_t)row*512 + tid*2;
  float2 xr = *(const float2*)(resf+ib);
  float2 xd = *(const float2*)(delta+ib);
  float x0 = xr.x+xd.x, x1 = xr.y+xd.y;
  float s = blockReduce(x0+x1, red);
  float mean = s*(1.f/512.f);
  float d0 = x0-mean, d1 = x1-mean;
  float q = blockReduce(d0*d0+d1*d1, red);
  float inv = 1.f/sqrtf(q*(1.f/512.f)+1e-5f);
  float2 gg = *(const float2*)(g+tid*2);
  float2 bb = *(const float2*)(be+tid*2);
  float r0 = d0*inv*gg.x + bb.x;
  float r1 = d1*inv*gg.y + bb.y;
  size_t ob = (size_t)row*ostride + ocol + tid*2;
  *(u32*)(outb+ob) = ((u32)f2bf(r1)<<16) | (u32)f2bf(r0);
  if (outf){ *(float2*)(outf + ib) = make_float2(r0,r1); }
}

// ---------------- BatchNorm (training stats over 10240 rows) ----------------
__global__ __launch_bounds__(512) void bn_part(const float* __restrict__ y,
                                               float* __restrict__ psum, float* __restrict__ psq){
  int c = threadIdx.x, blk = blockIdx.x;   // 64 blocks x 512 threads
  float s = 0.f, q = 0.f;
  for (int r = blk; r < 10240; r += 64){
    float v = y[(size_t)r*512 + c];
    s += v; q += v*v;
  }
  psum[blk*512+c] = s; psq[blk*512+c] = q;
}

__global__ __launch_bounds__(512) void bn_fin(const float* __restrict__ psum,
                                              const float* __restrict__ psq,
                                              const float* __restrict__ g,
                                              const float* __restrict__ b,
                                              float* __restrict__ scale, float* __restrict__ shift){
  int c = threadIdx.x;
  float s = 0.f, q = 0.f;
  for (int k=0;k<64;++k){ s += psum[k*512+c]; q += psq[k*512+c]; }
  float m = s*(1.f/10240.f);
  float var = q*(1.f/10240.f) - m*m;
  float sc = g[c]/sqrtf(var + 1e-5f);
  scale[c] = sc; shift[c] = b[c] - m*sc;
}

__global__ __launch_bounds__(256) void bn_apply(const float* __restrict__ y,
                                                const float* __restrict__ scale,
                                                const float* __restrict__ shift,
                                                u16* __restrict__ out){
  long i4 = ((long)blockIdx.x*256 + threadIdx.x)*4;
  if (i4 < (long)10240*512){
    int c = (int)(i4 & 511);
    f32x4 v  = *(const f32x4*)(y+i4);
    f32x4 sc = *(const f32x4*)(scale+c);
    f32x4 sh = *(const f32x4*)(shift+c);
    f32x4 r;
    #pragma unroll
    for (int k=0;k<4;++k){
      float t = v[k]*sc[k] + sh[k];
      r[k] = t > 0.f ? t : 0.2f*t;             // LeakyReLU(0.2)
    }
    u16x4 o; o.x=f2bf(r[0]); o.y=f2bf(r[1]); o.z=f2bf(r[2]); o.w=f2bf(r[3]);
    *(u16x4*)(out+i4) = o;
  }
}

extern "C" void kernel_launch(void* const* d_in, const int* in_sizes, int n_in,
                              void* d_out, int out_size, void* d_ws, size_t ws_size,
                              hipStream_t stream){
  const float* verts = (const float*)d_in[0];
  const float* F     = (const float*)d_in[1];
  const float* ew[2][16];
  for (int e=0;e<2;++e) for (int i=0;i<16;++i) ew[e][i] = (const float*)d_in[2+e*16+i];
  const float* fus_w1  = (const float*)d_in[34];
  const float* fus_b1  = (const float*)d_in[35];
  const float* fus_bng = (const float*)d_in[36];
  const float* fus_bnb = (const float*)d_in[37];
  const float* fus_w2  = (const float*)d_in[38];
  const float* fus_b2  = (const float*)d_in[39];

  const int M = 10240;
  size_t off = 0;
  auto alloc = [&](size_t bytes)->void*{
    void* p = (char*)d_ws + off; off = (off + bytes + 255) & ~(size_t)255; return p;
  };
  u16 *wtqkv[2],*wto[2],*wtw1[2],*wtw2[2];
  float* bqkv[2];
  for (int e=0;e<2;++e){
    wtqkv[e] = (u16*)alloc((size_t)3072*512*2);   // [N=3072][K=512] = q|k|v stacked
    wto[e]   = (u16*)alloc((size_t)512*1024*2);
    wtw1[e]  = (u16*)alloc((size_t)2048*512*2);
    wtw2[e]  = (u16*)alloc((size_t)512*2048*2);
    bqkv[e]  = (float*)alloc(3072*4);
  }
  u16*  wtf1 = (u16*)alloc((size_t)512*1024*2);   // [N=512][K=1024]
  u16*  wtf2 = (u16*)alloc((size_t)512*512*2);
  u16*  Fb   = (u16*)alloc((size_t)M*512*2);
  u16*  QKVb = (u16*)alloc((size_t)M*3072*2);     // 60 MB
  u16*  H1   = (u16*)alloc((size_t)M*2048*2);
  float* PF  = (float*)alloc((size_t)M*512*4);
  u16*  X1b  = (u16*)alloc((size_t)M*512*2);
  u16*  YC   = (u16*)alloc((size_t)M*1024*2);
  unsigned char* nbr1 = (unsigned char*)alloc(256*40*4);
  unsigned char* nbr2 = (unsigned char*)alloc(256*40*8);
  float* psum = (float*)alloc(64*512*4);
  float* psq  = (float*)alloc(64*512*4);
  float* bnsc = (float*)alloc(512*4);
  float* bnsh = (float*)alloc(512*4);
  // time-disjoint aliases (stream-ordered; see per-encoder schedule)
  u16*   OB  = H1;                               // attn out, dead before FFN1 writes H1
  float* X1f = (float*)QKVb;                     // LN1 f32 out; QKV dead after attn
  float* Y1  = (float*)QKVb;                     // fusion GEMM f32 out (post-encoders)
  u16*   Y2  = (u16*)((char*)QKVb + (size_t)M*512*4);  // BN out, disjoint from Y1

  if (off > ws_size){      // ws too small: distinguishable sentinel
    long n = out_size;
    fill_kernel<<<(unsigned)((n+255)/256),256,0,stream>>>((float*)d_out, 12345.0f, n);
    return;
  }

  // ---- prep: weight transposes (QKV stacked along N), F->bf16, KNN ----
  for (int e=0;e<2;++e){
    wt_kernel<<<dim3(32,16),dim3(32,8),0,stream>>>(ew[e][0],  wtqkv[e],               512, 1024);
    wt_kernel<<<dim3(32,16),dim3(32,8),0,stream>>>(ew[e][2],  wtqkv[e]+(size_t)1024*512, 512, 1024);
    wt_kernel<<<dim3(32,16),dim3(32,8),0,stream>>>(ew[e][4],  wtqkv[e]+(size_t)2048*512, 512, 1024);
    wt_kernel<<<dim3(16,32),dim3(32,8),0,stream>>>(ew[e][6],  wto[e],  1024, 512);
    wt_kernel<<<dim3(64,16),dim3(32,8),0,stream>>>(ew[e][10], wtw1[e], 512, 2048);
    wt_kernel<<<dim3(16,64),dim3(32,8),0,stream>>>(ew[e][12], wtw2[e], 2048, 512);
    catb_kernel<<<12,256,0,stream>>>(ew[e][1], ew[e][3], ew[e][5], bqkv[e]);
  }
  wt_kernel<<<dim3(16,32),dim3(32,8),0,stream>>>(fus_w1, wtf1, 1024, 512);
  wt_kernel<<<dim3(16,16),dim3(32,8),0,stream>>>(fus_w2, wtf2, 512, 512);
  cvt_kernel<<<5120,256,0,stream>>>(F, Fb, (long)M*512/4);
  knn_kernel<<<256,256,0,stream>>>(verts, nbr1, nbr2);

  // ---- encoders ----
  for (int e=0;e<2;++e){
    gemm_bt<0,1><<<dim3(80,24),256,0,stream>>>(Fb, wtqkv[e], bqkv[e], QKVb, M, 3072, 512);
    if (e == 0) attn_kernel<4><<<1024,256,0,stream>>>(QKVb, nbr1, OB);
    else        attn_kernel<8><<<1024,256,0,stream>>>(QKVb, nbr2, OB);
    gemm_bt<0,0><<<dim3(80,4),256,0,stream>>>(OB, wto[e], ew[e][7], PF, M, 512, 1024);
    ln_kernel<<<M,256,0,stream>>>(F, PF, ew[e][8], ew[e][9], X1b, 512, 0, X1f);
    gemm_bt<1,1><<<dim3(80,16),256,0,stream>>>(X1b, wtw1[e], ew[e][11], H1, M, 2048, 512);
    gemm_bt<0,0><<<dim3(80,4),256,0,stream>>>(H1, wtw2[e], ew[e][13], PF, M, 512, 2048);
    ln_kernel<<<M,256,0,stream>>>(X1f, PF, ew[e][14], ew[e][15], YC, 1024, e*512, nullptr);
  }

  // ---- fusion ----
  gemm_bt<0,0><<<dim3(80,4),256,0,stream>>>(YC, wtf1, fus_b1, Y1, M, 512, 1024);
  bn_part<<<64,512,0,stream>>>(Y1, psum, psq);
  bn_fin<<<1,512,0,stream>>>(psum, psq, fus_bng, fus_bnb, bnsc, bnsh);
  bn_apply<<<5120,256,0,stream>>>(Y1, bnsc, bnsh, Y2);
  gemm_bt<0,0><<<dim3(80,4),256,0,stream>>>(Y2, wtf2, fus_b2, d_out, M, 512, 512);
}

// Round 5
// 559.963 us; speedup vs baseline: 1.1913x; 1.0109x over previous
//
#include <hip/hip_runtime.h>

typedef unsigned short u16;
typedef unsigned int   u32;
typedef __attribute__((ext_vector_type(4))) float f32x4;
typedef __attribute__((ext_vector_type(8))) short short8;
typedef __attribute__((ext_vector_type(4))) unsigned short u16x4;

#define DEV __device__ __forceinline__
#define AS1 __attribute__((address_space(1)))
#define AS3 __attribute__((address_space(3)))

DEV float bf2f(u16 u){ return __uint_as_float(((u32)u)<<16); }
DEV u16 f2bf(float f){ u32 u=__float_as_uint(f); return (u16)((u + 0x7fffu + ((u>>16)&1u))>>16); }
DEV void g2lds16(const void* g, void* l){
  __builtin_amdgcn_global_load_lds((const AS1 void*)g, (AS3 void*)l, 16, 0, 0);
}

// ---------------- f32 [K][N] -> bf16 [N][K] transpose ----------------
__global__ __launch_bounds__(256) void wt_kernel(const float* __restrict__ W,
                                                 u16* __restrict__ WT, int K, int N){
  __shared__ u16 tile[32][33];
  int n0 = blockIdx.x*32, k0 = blockIdx.y*32;
  int tx = threadIdx.x, ty = threadIdx.y;            // (32,8)
  #pragma unroll
  for (int i=0;i<4;++i){
    int k = ty + i*8;
    tile[k][tx] = f2bf(W[(size_t)(k0+k)*N + n0 + tx]);
  }
  __syncthreads();
  #pragma unroll
  for (int i=0;i<4;++i){
    int n = ty + i*8;
    WT[(size_t)(n0+n)*K + k0 + tx] = tile[tx][n];
  }
}

// ---------------- f32 -> bf16 elementwise (x4 vectorized) ----------------
__global__ __launch_bounds__(256) void cvt_kernel(const float* __restrict__ in,
                                                  u16* __restrict__ out, long n4){
  long i = ((long)blockIdx.x*256 + threadIdx.x);
  if (i < n4){
    f32x4 v = *(const f32x4*)(in + i*4);
    u16x4 r; r.x=f2bf(v.x); r.y=f2bf(v.y); r.z=f2bf(v.z); r.w=f2bf(v.w);
    *(u16x4*)(out + i*4) = r;
  }
}

// ---------------- concat 3 bias vectors [1024] -> [3072] ----------------
__global__ __launch_bounds__(256) void catb_kernel(const float* __restrict__ a,
                                                   const float* __restrict__ b,
                                                   const float* __restrict__ c,
                                                   float* __restrict__ dst){
  int i = blockIdx.x*256 + threadIdx.x;
  if (i < 1024) dst[i] = a[i];
  else if (i < 2048) dst[i] = b[i-1024];
  else if (i < 3072) dst[i] = c[i-2048];
}

// ---------------- sentinel fill (ws too small diagnostic) ----------------
__global__ __launch_bounds__(256) void fill_kernel(float* p, float v, long n){
  long i = (long)blockIdx.x*256 + threadIdx.x;
  if (i < n) p[i] = v;
}

// ---------------- KNN: one wave per (batch,row), d per-lane in registers ----------------
__global__ __launch_bounds__(256) void knn_kernel(const float* __restrict__ verts,
                                                  unsigned char* __restrict__ nbr1,
                                                  unsigned char* __restrict__ nbr2){
  __shared__ float P[40][3];
  __shared__ float SQ[40];
  int b = blockIdx.x, tid = threadIdx.x, wave = tid>>6, lane = tid&63;
  if (tid < 40){
    float x = verts[((size_t)b*40+tid)*3+0];
    float y = verts[((size_t)b*40+tid)*3+1];
    float z = verts[((size_t)b*40+tid)*3+2];
    P[tid][0]=x; P[tid][1]=y; P[tid][2]=z;
    SQ[tid] = __fadd_rn(__fadd_rn(__fmul_rn(x,x),__fmul_rn(y,y)),__fmul_rn(z,z));
  }
  __syncthreads();
  for (int i = wave; i < 40; i += 4){
    float d = 3.0e38f;
    if (lane < 40){
      int j = lane;
      float dot = __fadd_rn(__fadd_rn(__fmul_rn(P[i][0],P[j][0]),
                                      __fmul_rn(P[i][1],P[j][1])),
                            __fmul_rn(P[i][2],P[j][2]));
      d = __fadd_rn(__fadd_rn(__fmul_rn(-2.f,dot), SQ[j]), SQ[i]);
    }
    bool taken = false;
    #pragma unroll
    for (int s=0;s<8;++s){
      float v = taken ? 3.0e38f : d;
      float m = v;
      #pragma unroll
      for (int o=32;o;o>>=1) m = fminf(m, __shfl_xor(m, o));
      unsigned long long mask = __ballot(v == m);
      int bj = __ffsll((unsigned long long)mask) - 1;   // lowest index among ties (stable)
      if (lane == bj) taken = true;
      if (lane == 0){
        if (s < 4) nbr1[((size_t)b*40+i)*4+s] = (unsigned char)bj;
        nbr2[((size_t)b*40+i)*8+s] = (unsigned char)bj;
      }
    }
  }
}

// ---------------- bf16 MFMA GEMM: C[M,N] = A[M,K] @ BT[N,K]^T + bias ----------------
// 128x128 tile, BK=32, 4 waves (2x2), 4x4 16x16x32 fragments per wave (m97 structure)
// LDS chunk-XOR swizzle (T2, rule #21 both-sides): row-major [128][32]bf16 rows are 64B,
// fragment reads (16 lanes, fixed fc) were 8-way bank conflicts. Physical chunk =
// logical chunk ^ ((row>>1)&3): write side pre-swizzles the GLOBAL source per lane
// (LDS dest stays linear for global_load_lds), read side applies the same involution.
template<int RELU, int OUTBF>
__global__ __launch_bounds__(256, 4) void gemm_bt(const u16* __restrict__ A,
                                                  const u16* __restrict__ BT,
                                                  const float* __restrict__ bias,
                                                  void* __restrict__ Cout,
                                                  int M, int N, int K){
  __shared__ u16 As[128*32];
  __shared__ u16 Bs[128*32];
  const int tid  = threadIdx.x;
  const int wave = tid>>6, lane = tid&63;
  const int wr = (wave>>1)<<6, wc = (wave&1)<<6;
  const int row0 = blockIdx.x<<7, col0 = blockIdx.y<<7;
  f32x4 acc[4][4];
  #pragma unroll
  for (int i=0;i<4;++i)
    #pragma unroll
    for (int j=0;j<4;++j) acc[i][j] = (f32x4){0.f,0.f,0.f,0.f};

  const int rL = lane>>2;             // row within 16-row staging group
  const int ch = lane&3;              // 16B chunk index within row
  const int fr = lane&15, fc = lane>>4;
  const short8* Asv = (const short8*)As;
  const short8* Bsv = (const short8*)Bs;

  for (int kt=0; kt<K; kt+=32){
    #pragma unroll
    for (int c=0;c<2;++c){
      int lo = c*4096 + wave*1024;             // wave-uniform LDS byte base (linear dest)
      int r  = c*64 + wave*16 + rL;
      int kk = ((ch ^ ((r>>1)&3))<<3);         // pre-swizzled global source chunk
      g2lds16(A  + (size_t)(row0+r)*K + kt + kk, (char*)As + lo);
      g2lds16(BT + (size_t)(col0+r)*K + kt + kk, (char*)Bs + lo);
    }
    __syncthreads();                            // drains vmcnt(0) + barrier
    short8 a[4], b[4];
    #pragma unroll
    for (int i=0;i<4;++i){
      int rowA = wr + i*16 + fr;
      int rowB = wc + i*16 + fr;
      a[i] = Asv[rowA*4 + (fc ^ ((rowA>>1)&3))];
      b[i] = Bsv[rowB*4 + (fc ^ ((rowB>>1)&3))];
    }
    #pragma unroll
    for (int i=0;i<4;++i)
      #pragma unroll
      for (int j=0;j<4;++j)
        acc[i][j] = __builtin_amdgcn_mfma_f32_16x16x32_bf16(a[i], b[j], acc[i][j], 0,0,0);
    __syncthreads();
  }
  #pragma unroll
  for (int i=0;i<4;++i){
    int mrow = row0 + wr + i*16 + fc*4;
    #pragma unroll
    for (int j=0;j<4;++j){
      int ncol = col0 + wc + j*16 + fr;
      float bv = bias[ncol];
      #pragma unroll
      for (int r=0;r<4;++r){
        float v = acc[i][j][r] + bv;
        if (RELU) v = v > 0.f ? v : 0.f;
        if (OUTBF) ((u16*)Cout)[(size_t)(mrow+r)*N + ncol] = f2bf(v);
        else       ((float*)Cout)[(size_t)(mrow+r)*N + ncol] = v;
      }
    }
  }
}

// ---------------- sparse masked attention: K/V staged in LDS, all-bf16 inputs ----------------
// block per (b,h), 4 waves; QKV combined [M][3072]: Q at h*256, K at 1024+h*256, V at 2048+h*256
template<int KNB>
__global__ __launch_bounds__(256) void attn_kernel(const u16* __restrict__ QKV,
                                                   const unsigned char* __restrict__ nbr,
                                                   u16* __restrict__ O){
  __shared__ u16 KV[2][40*256];    // [0]=K rows, [1]=V rows (bf16)
  int b = blockIdx.x>>2, h = blockIdx.x&3;
  int tid = threadIdx.x, wave = tid>>6, lane = tid&63;
  const size_t rowb = (size_t)b*40;
  for (int c = tid; c < 1280; c += 256){          // 40 rows x 32 chunks of 16B
    int row = c >> 5, col = (c & 31) << 3;
    size_t src = (rowb+row)*3072 + h*256 + col;
    *(short8*)&KV[0][row*256+col] = *(const short8*)(QKV + src + 1024);
    *(short8*)&KV[1][row*256+col] = *(const short8*)(QKV + src + 2048);
  }
  __syncthreads();
  for (int i = wave; i < 40; i += 4){
    int js[KNB];
    if (KNB == 4){
      u32 p = *(const u32*)(nbr + (rowb+i)*4);
      js[0]=p&255; js[1]=(p>>8)&255; js[2]=(p>>16)&255; js[3]=(p>>24)&255;
    } else {
      u32 p0 = *(const u32*)(nbr + (rowb+i)*8);
      u32 p1 = *(const u32*)(nbr + (rowb+i)*8 + 4);
      js[0]=p0&255; js[1]=(p0>>8)&255; js[2]=(p0>>16)&255; js[3]=(p0>>24)&255;
      js[4]=p1&255; js[5]=(p1>>8)&255; js[6]=(p1>>16)&255; js[7]=(p1>>24)&255;
    }
    u16x4 qv = *(const u16x4*)(QKV + (rowb+i)*3072 + h*256 + lane*4);
    float q0=bf2f(qv.x), q1=bf2f(qv.y), q2=bf2f(qv.z), q3=bf2f(qv.w);
    float s[KNB];
    #pragma unroll
    for (int jj=0;jj<KNB;++jj){
      u16x4 kv = *(const u16x4*)&KV[0][js[jj]*256 + lane*4];
      s[jj] = q0*bf2f(kv.x) + q1*bf2f(kv.y) + q2*bf2f(kv.z) + q3*bf2f(kv.w);
    }
    #pragma unroll
    for (int jj=0;jj<KNB;++jj){
      #pragma unroll
      for (int o=32;o;o>>=1) s[jj] += __shfl_xor(s[jj], o);
      s[jj] *= 0.0625f;                       // 1/sqrt(256)
    }
    float m = s[0];
    #pragma unroll
    for (int jj=1;jj<KNB;++jj) m = fmaxf(m, s[jj]);
    float sum = 0.f;
    #pragma unroll
    for (int jj=0;jj<KNB;++jj){ s[jj] = expf(s[jj]-m); sum += s[jj]; }
    float inv = 1.f/sum;
    float o0=0.f,o1=0.f,o2=0.f,o3=0.f;
    #pragma unroll
    for (int jj=0;jj<KNB;++jj){
      float w = s[jj]*inv;
      u16x4 vv = *(const u16x4*)&KV[1][js[jj]*256 + lane*4];
      o0 += w*bf2f(vv.x); o1 += w*bf2f(vv.y); o2 += w*bf2f(vv.z); o3 += w*bf2f(vv.w);
    }
    u16x4 r; r.x=f2bf(o0); r.y=f2bf(o1); r.z=f2bf(o2); r.w=f2bf(o3);
    *(u16x4*)(O + (rowb+i)*1024 + h*256 + lane*4) = r;
  }
}

// ---------------- residual + LayerNorm (row = 512), float2-vectorized ----------------
DEV float blockReduce(float v, float* red){
  #pragma unroll
  for (int o=32;o;o>>=1) v += __shfl_xor(v, o);
  int lane = threadIdx.x&63, w = threadIdx.x>>6;
  if (lane==0) red[w] = v;
  __syncthreads();
  float t = red[0]+red[1]+red[2]+red[3];
  __syncthreads();
  return t;
}

__global__ __launch_bounds__(256) void ln_kernel(const float* __restrict__ resf,
                                                 const float* __restrict__ delta,
                                                 const float* __restrict__ g,
                                                 const float* __restrict__ be,
                                                 u16* __restrict__ outb, int ostride, int ocol,
                                                 float* __restrict__ outf){
  __shared__ float red[4];
  int row = blockIdx.x, tid = threadIdx.x;
  size_t ib = (size_t)row*512 + tid*2;
  float2 xr = *(const float2*)(resf+ib);
  float2 xd = *(const float2*)(delta+ib);
  float x0 = xr.x+xd.x, x1 = xr.y+xd.y;
  float s = blockReduce(x0+x1, red);
  float mean = s*(1.f/512.f);
  float d0 = x0-mean, d1 = x1-mean;
  float q = blockReduce(d0*d0+d1*d1, red);
  float inv = 1.f/sqrtf(q*(1.f/512.f)+1e-5f);
  float2 gg = *(const float2*)(g+tid*2);
  float2 bb = *(const float2*)(be+tid*2);
  float r0 = d0*inv*gg.x + bb.x;
  float r1 = d1*inv*gg.y + bb.y;
  size_t ob = (size_t)row*ostride + ocol + tid*2;
  *(u32*)(outb+ob) = ((u32)f2bf(r1)<<16) | (u32)f2bf(r0);
  if (outf){ *(float2*)(outf + ib) = make_float2(r0,r1); }
}

// ---------------- BatchNorm (training stats over 10240 rows) ----------------
__global__ __launch_bounds__(512) void bn_part(const float* __restrict__ y,
                                               float* __restrict__ psum, float* __restrict__ psq){
  int c = threadIdx.x, blk = blockIdx.x;   // 64 blocks x 512 threads
  float s = 0.f, q = 0.f;
  for (int r = blk; r < 10240; r += 64){
    float v = y[(size_t)r*512 + c];
    s += v; q += v*v;
  }
  psum[blk*512+c] = s; psq[blk*512+c] = q;
}

__global__ __launch_bounds__(512) void bn_fin(const float* __restrict__ psum,
                                              const float* __restrict__ psq,
                                              const float* __restrict__ g,
                                              const float* __restrict__ b,
                                              float* __restrict__ scale, float* __restrict__ shift){
  int c = threadIdx.x;
  float s = 0.f, q = 0.f;
  for (int k=0;k<64;++k){ s += psum[k*512+c]; q += psq[k*512+c]; }
  float m = s*(1.f/10240.f);
  float var = q*(1.f/10240.f) - m*m;
  float sc = g[c]/sqrtf(var + 1e-5f);
  scale[c] = sc; shift[c] = b[c] - m*sc;
}

__global__ __launch_bounds__(256) void bn_apply(const float* __restrict__ y,
                                                const float* __restrict__ scale,
                                                const float* __restrict__ shift,
                                                u16* __restrict__ out){
  long i4 = ((long)blockIdx.x*256 + threadIdx.x)*4;
  if (i4 < (long)10240*512){
    int c = (int)(i4 & 511);
    f32x4 v  = *(const f32x4*)(y+i4);
    f32x4 sc = *(const f32x4*)(scale+c);
    f32x4 sh = *(const f32x4*)(shift+c);
    f32x4 r;
    #pragma unroll
    for (int k=0;k<4;++k){
      float t = v[k]*sc[k] + sh[k];
      r[k] = t > 0.f ? t : 0.2f*t;             // LeakyReLU(0.2)
    }
    u16x4 o; o.x=f2bf(r[0]); o.y=f2bf(r[1]); o.z=f2bf(r[2]); o.w=f2bf(r[3]);
    *(u16x4*)(out+i4) = o;
  }
}

extern "C" void kernel_launch(void* const* d_in, const int* in_sizes, int n_in,
                              void* d_out, int out_size, void* d_ws, size_t ws_size,
                              hipStream_t stream){
  const float* verts = (const float*)d_in[0];
  const float* F     = (const float*)d_in[1];
  const float* ew[2][16];
  for (int e=0;e<2;++e) for (int i=0;i<16;++i) ew[e][i] = (const float*)d_in[2+e*16+i];
  const float* fus_w1  = (const float*)d_in[34];
  const float* fus_b1  = (const float*)d_in[35];
  const float* fus_bng = (const float*)d_in[36];
  const float* fus_bnb = (const float*)d_in[37];
  const float* fus_w2  = (const float*)d_in[38];
  const float* fus_b2  = (const float*)d_in[39];

  const int M = 10240;
  size_t off = 0;
  auto alloc = [&](size_t bytes)->void*{
    void* p = (char*)d_ws + off; off = (off + bytes + 255) & ~(size_t)255; return p;
  };
  u16 *wtqkv[2],*wto[2],*wtw1[2],*wtw2[2];
  float* bqkv[2];
  for (int e=0;e<2;++e){
    wtqkv[e] = (u16*)alloc((size_t)3072*512*2);   // [N=3072][K=512] = q|k|v stacked
    wto[e]   = (u16*)alloc((size_t)512*1024*2);
    wtw1[e]  = (u16*)alloc((size_t)2048*512*2);
    wtw2[e]  = (u16*)alloc((size_t)512*2048*2);
    bqkv[e]  = (float*)alloc(3072*4);
  }
  u16*  wtf1 = (u16*)alloc((size_t)512*1024*2);   // [N=512][K=1024]
  u16*  wtf2 = (u16*)alloc((size_t)512*512*2);
  u16*  Fb   = (u16*)alloc((size_t)M*512*2);
  u16*  QKVb = (u16*)alloc((size_t)M*3072*2);     // 60 MB
  u16*  H1   = (u16*)alloc((size_t)M*2048*2);
  float* PF  = (float*)alloc((size_t)M*512*4);
  u16*  X1b  = (u16*)alloc((size_t)M*512*2);
  u16*  YC   = (u16*)alloc((size_t)M*1024*2);
  unsigned char* nbr1 = (unsigned char*)alloc(256*40*4);
  unsigned char* nbr2 = (unsigned char*)alloc(256*40*8);
  float* psum = (float*)alloc(64*512*4);
  float* psq  = (float*)alloc(64*512*4);
  float* bnsc = (float*)alloc(512*4);
  float* bnsh = (float*)alloc(512*4);
  // time-disjoint aliases (stream-ordered; see per-encoder schedule)
  u16*   OB  = H1;                               // attn out, dead before FFN1 writes H1
  float* X1f = (float*)QKVb;                     // LN1 f32 out; QKV dead after attn
  float* Y1  = (float*)QKVb;                     // fusion GEMM f32 out (post-encoders)
  u16*   Y2  = (u16*)((char*)QKVb + (size_t)M*512*4);  // BN out, disjoint from Y1

  if (off > ws_size){      // ws too small: distinguishable sentinel
    long n = out_size;
    fill_kernel<<<(unsigned)((n+255)/256),256,0,stream>>>((float*)d_out, 12345.0f, n);
    return;
  }

  // ---- prep: weight transposes (QKV stacked along N), F->bf16, KNN ----
  for (int e=0;e<2;++e){
    wt_kernel<<<dim3(32,16),dim3(32,8),0,stream>>>(ew[e][0],  wtqkv[e],               512, 1024);
    wt_kernel<<<dim3(32,16),dim3(32,8),0,stream>>>(ew[e][2],  wtqkv[e]+(size_t)1024*512, 512, 1024);
    wt_kernel<<<dim3(32,16),dim3(32,8),0,stream>>>(ew[e][4],  wtqkv[e]+(size_t)2048*512, 512, 1024);
    wt_kernel<<<dim3(16,32),dim3(32,8),0,stream>>>(ew[e][6],  wto[e],  1024, 512);
    wt_kernel<<<dim3(64,16),dim3(32,8),0,stream>>>(ew[e][10], wtw1[e], 512, 2048);
    wt_kernel<<<dim3(16,64),dim3(32,8),0,stream>>>(ew[e][12], wtw2[e], 2048, 512);
    catb_kernel<<<12,256,0,stream>>>(ew[e][1], ew[e][3], ew[e][5], bqkv[e]);
  }
  wt_kernel<<<dim3(16,32),dim3(32,8),0,stream>>>(fus_w1, wtf1, 1024, 512);
  wt_kernel<<<dim3(16,16),dim3(32,8),0,stream>>>(fus_w2, wtf2, 512, 512);
  cvt_kernel<<<5120,256,0,stream>>>(F, Fb, (long)M*512/4);
  knn_kernel<<<256,256,0,stream>>>(verts, nbr1, nbr2);

  // ---- encoders ----
  for (int e=0;e<2;++e){
    gemm_bt<0,1><<<dim3(80,24),256,0,stream>>>(Fb, wtqkv[e], bqkv[e], QKVb, M, 3072, 512);
    if (e == 0) attn_kernel<4><<<1024,256,0,stream>>>(QKVb, nbr1, OB);
    else        attn_kernel<8><<<1024,256,0,stream>>>(QKVb, nbr2, OB);
    gemm_bt<0,0><<<dim3(80,4),256,0,stream>>>(OB, wto[e], ew[e][7], PF, M, 512, 1024);
    ln_kernel<<<M,256,0,stream>>>(F, PF, ew[e][8], ew[e][9], X1b, 512, 0, X1f);
    gemm_bt<1,1><<<dim3(80,16),256,0,stream>>>(X1b, wtw1[e], ew[e][11], H1, M, 2048, 512);
    gemm_bt<0,0><<<dim3(80,4),256,0,stream>>>(H1, wtw2[e], ew[e][13], PF, M, 512, 2048);
    ln_kernel<<<M,256,0,stream>>>(X1f, PF, ew[e][14], ew[e][15], YC, 1024, e*512, nullptr);
  }

  // ---- fusion ----
  gemm_bt<0,0><<<dim3(80,4),256,0,stream>>>(YC, wtf1, fus_b1, Y1, M, 512, 1024);
  bn_part<<<64,512,0,stream>>>(Y1, psum, psq);
  bn_fin<<<1,512,0,stream>>>(psum, psq, fus_bng, fus_bnb, bnsc, bnsh);
  bn_apply<<<5120,256,0,stream>>>(Y1, bnsc, bnsh, Y2);
  gemm_bt<0,0><<<dim3(80,4),256,0,stream>>>(Y2, wtf2, fus_b2, d_out, M, 512, 512);
}